// Round 9
// baseline (682.197 us; speedup 1.0000x reference)
//
#include <hip/hip_runtime.h>

#define CC 256      // checks
#define VV 512      // variables
#define MAXRD 26    // row-degree cap (validated rounds 0-8, absmax 0)
#define MAXCD 18    // col-degree cap (validated)
#define PSTRIDE 27  // deg+1 <= 27 prefix states
#define CLU 6       // fixed-unroll gather depth (tail loop for cd>6)

typedef __attribute__((address_space(1))) float gfloat;   // true global ops (vmcnt only)

__device__ __forceinline__ float sgnf(float x) {
    return (x > 0.f) ? 1.f : ((x < 0.f) ? -1.f : 0.f);
}
__device__ __forceinline__ float phi_f(float x) {
    return 2.0f * atanf(expf(0.5f * x));
}
// LDS-only fence + raw barrier (no flat ops anywhere -> lgkmcnt is pure LDS)
__device__ __forceinline__ void lds_barrier() {
    asm volatile("s_waitcnt lgkmcnt(0)" ::: "memory");
    __builtin_amdgcn_sched_barrier(0);
    __builtin_amdgcn_s_barrier();
    __builtin_amdgcn_sched_barrier(0);
}

__global__ __launch_bounds__(256)
void ldpc_bp9(const float* __restrict__ llr_g, const int* __restrict__ H_g,
              const int* __restrict__ it_g, int* __restrict__ out_g,
              float* __restrict__ ws)
{
    __shared__ float              llr_s[VV];          //  2048 B
    __shared__ unsigned int       rsign[CC];          //  1024 B
    __shared__ unsigned int       rzero[CC];          //  1024 B
    __shared__ unsigned short     rdeg_s[CC];         //   512 B
    __shared__ float              Pst[CC][PSTRIDE];   // 27648 B
    __shared__ unsigned short     clistT[MAXCD][CC];  //  9216 B (pad=256)
    __shared__ unsigned short     cdeg_s[CC];         //   512 B
    __shared__ float              colbuf[2][2][257];  //  4112 B  [parity][A,B][cell]
    __shared__ float              ring[8][CC];        //  8192 B  last-8 step rows
    __shared__ unsigned long long rowmask[CC][4];     //  8192 B
    __shared__ unsigned char      rowpre[CC][4];      //  1024 B
    // total 63,504 B < 64 KB static

    const int j  = threadIdx.x;
    const int wv = j >> 6, ln = j & 63;
    gfloat* __restrict__ mg = (gfloat*)ws;  // mg[thread*CC + slot]: thread's val at step == slot (mod 256)

    // ---- setup (validated lineage) + robust zero-init of ring/colbufs ----
    llr_s[j] = llr_g[j]; llr_s[j + CC] = llr_g[j + CC];
    __syncthreads();
    {   int d = 0; unsigned int sb = 0, zb = 0;
        const int4* hrow = (const int4*)(H_g + j * VV);
        for (int g = 0; g < VV / 4; ++g) {
            int4 h = hrow[g]; const int v = g * 4;
            if (h.x) { if (d < MAXRD) { float l = llr_s[v+0]; sb |= (l < 0.f) << d; zb |= (l == 0.f) << d; } ++d; }
            if (h.y) { if (d < MAXRD) { float l = llr_s[v+1]; sb |= (l < 0.f) << d; zb |= (l == 0.f) << d; } ++d; }
            if (h.z) { if (d < MAXRD) { float l = llr_s[v+2]; sb |= (l < 0.f) << d; zb |= (l == 0.f) << d; } ++d; }
            if (h.w) { if (d < MAXRD) { float l = llr_s[v+3]; sb |= (l < 0.f) << d; zb |= (l == 0.f) << d; } ++d; }
        }
        rdeg_s[j] = (unsigned short)(d < MAXRD ? d : MAXRD);
        rsign[j] = sb; rzero[j] = zb;
    }
    {   int d = 0;
        for (int c = 0; c < CC; ++c) {
            const int h = H_g[c * VV + j];
            const unsigned long long m = __ballot(h != 0);
            if (ln == 0) rowmask[c][wv] = m;
            if (h) { if (d < MAXCD) clistT[d][j] = (unsigned short)c; ++d; }
        }
        cdeg_s[j] = (unsigned short)(d < MAXCD ? d : MAXCD);
        for (int k = d; k < MAXCD; ++k) clistT[k][j] = 256;
    }
    colbuf[0][0][j] = 0.f; colbuf[0][1][j] = 0.f;
    colbuf[1][0][j] = 0.f; colbuf[1][1][j] = 0.f;
    for (int r = 0; r < 8; ++r) ring[r][j] = 0.f;
    if (j == 0) {
        colbuf[0][0][256] = 0.f; colbuf[0][1][256] = 0.f;
        colbuf[1][0][256] = 0.f; colbuf[1][1][256] = 0.f;
    }
    __syncthreads();
    {   const int p1c = __popcll(rowmask[j][0]);
        const int p2c = p1c + __popcll(rowmask[j][1]);
        const int p3c = p2c + __popcll(rowmask[j][2]);
        rowpre[j][0] = 0; rowpre[j][1] = (unsigned char)p1c;
        rowpre[j][2] = (unsigned char)p2c; rowpre[j][3] = (unsigned char)p3c;
    }
    const int cl0 = clistT[0][j], cl1 = clistT[1][j], cl2 = clistT[2][j];
    const int cl3 = clistT[3][j], cl4 = clistT[4][j], cl5 = clistT[5][j];
    const int cd  = cdeg_s[j];
    __syncthreads();

    const int   max_iter = it_g[0];
    const int   total    = max_iter * CC;          // multiple of 2 (CC even)
    const float T05      = tanhf(0.5f);
    const float sgj      = sgnf(llr_s[j]);

    float svA_base = 0.f, svA_bi = 0.f, svA_cbs = 0.f; int svA_hv = 0;
    float svB_base = 0.f, svB_bi = 0.f, svB_cbs = 0.f; int svB_hv = 0;
    float pfu0 = 0.f, pfu1 = 0.f;
    float fprod = 1.0f;

    #pragma unroll 1
    for (int Ts = 0; Ts < total; Ts += 2) {        // section = steps {Ts, Ts+1}
        const int s   = Ts & 255;                  // even, <= 254
        const int X1v = s + 1;                     // never wraps within section
        const int X2v = (Ts + 2) & 255;
        const int X3v = (Ts + 3) & 255;
        const int pr  = (Ts >> 1) & 1;
        const float* cbA = colbuf[pr][0];          // column s      (step Ts)
        const float* cbB = colbuf[pr][1];          // column X1v   (step Ts+1; cell s stale -> dval)
        float* nxA = colbuf[pr ^ 1][0];            // column X2v for next section
        float* nxB = colbuf[pr ^ 1][1];            // column X3v for next section

        // ---- early issues: all independent loads up front ----
        const float gA0 = cbA[cl0], gA1 = cbA[cl1], gA2 = cbA[cl2];
        const float gA3 = cbA[cl3], gA4 = cbA[cl4], gA5 = cbA[cl5];
        const float gB0 = cbB[cl0], gB1 = cbB[cl1], gB2 = cbB[cl2];
        const float gB3 = cbB[cl3], gB4 = cbB[cl4], gB5 = cbB[cl5];
        const unsigned long long rmA = rowmask[s][wv];
        const unsigned long long rmB = rowmask[X1v][wv];
        const int p = (Ts + 1) - ((Ts + 1 - j) & 255);   // last step == j (mod 256), <= Ts+1
        const float ringvA = ring[p & 7][X2v];           // valid only for p in [Ts-8, Ts-3]
        const float ringvB = ring[p & 7][X3v];
        const float pfi0 = mg[((Ts + 4) & 255) * CC + j];  // for column Ts+4 (next section's X2)
        const float pfi1 = mg[((Ts + 5) & 255) * CC + j];  // for column Ts+5 (next section's X3)
        const int dc0 = clistT[0][X1v], dc1 = clistT[1][X1v], dc2 = clistT[2][X1v];
        const int dc3 = clistT[3][X1v], dc4 = clistT[4][X1v], dc5 = clistT[5][X1v];
        const int cdd = cdeg_s[X1v];

        // ---- deferred finish of rows Ts-2, Ts-1 (register-only phi) ----
        float vnpA = 0.f, vnpB = 0.f;
        if (Ts >= 2) {
            if (svA_hv) { float vn = phi_f(svA_bi); vnpA = phi_f(svA_base + (vn - svA_cbs)); }
            else        vnpA = phi_f(svA_base);
            if (svB_hv) { float vn = phi_f(svB_bi); vnpB = phi_f(svB_base + (vn - svB_cbs)); }
            else        vnpB = phi_f(svB_base);
            ring[(Ts - 2) & 7][j] = vnpA;          // slots disjoint from this section's reads
            ring[(Ts - 1) & 7][j] = vnpB;
            mg[j * CC + ((Ts - 2) & 255)] = vnpA;  // global fire-and-forget
            mg[j * CC + ((Ts - 1) & 255)] = vnpB;
            if (j < 4) {                            // on-line final product, ascending rows
                if (Ts - 2 >= total - CC) fprod *= tanhf(0.5f * vnpA);
                if (Ts - 1 >= total - CC) fprod *= tanhf(0.5f * vnpB);
            }
        }

        // ---- p1 at pass start (thread = check j) ----
        if (s == 0) {
            const int pass = Ts >> 8;
            const int deg  = rdeg_s[j];
            const unsigned int sb = rsign[j], zb = rzero[j];
            float NP = 1.0f;
            for (int k = 0; k <= deg; ++k) {
                float P = NP;
                for (int idx = k; idx < deg; ++idx) {        // old tail, ascending v
                    float told;
                    if (pass == 0) told = T05;
                    else {
                        const float sg = ((zb >> idx) & 1u) ? 0.0f
                                       : (((sb >> idx) & 1u) ? -1.0f : 1.0f);
                        told = tanhf(0.5f * (sg * Pst[j][idx]));
                    }
                    P *= told;
                }
                Pst[j][k] = P;                               // in-place safe (idx >= k)
                if (k < deg) {
                    const float sg = ((zb >> k) & 1u) ? 0.0f
                                   : (((sb >> k) & 1u) ? -1.0f : 1.0f);
                    NP *= tanhf(0.5f * (sg * P));
                }
            }
            lds_barrier();
        }

        // ---- diag: dval = val_{Ts}[X1v], uniform redundant compute (bit-exact) ----
        float dsum = 0.0f;                                   // ascending-c, left-assoc
        dsum += cbA[dc0]; dsum += cbA[dc1]; dsum += cbA[dc2];
        dsum += cbA[dc3]; dsum += cbA[dc4]; dsum += cbA[dc5];
        for (int k = CLU; k < cdd; ++k) dsum += cbA[clistT[k][X1v]];
        const int kjd = (int)rowpre[s][X1v >> 6]
                      + __popcll(rowmask[s][X1v >> 6] & ((1ull << (X1v & 63)) - 1ull));
        const float bX1 = dsum - sgnf(llr_s[X1v]) * Pst[s][kjd];
        const bool diag_hit = (rowmask[s][X1v >> 6] >> (X1v & 63)) & 1ull;  // X1v > s always
        float dval;
        if (diag_hit) {                                      // wave-uniform scalar branch
            float bs_ = 0.0f;
            const int cds = cdeg_s[s];
            for (int k = 0; k < cds; ++k) bs_ += cbA[clistT[k][s]];
            const int kis = (int)rowpre[s][s >> 6]
                          + __popcll(rowmask[s][s >> 6] & ((1ull << (s & 63)) - 1ull));
            const float bis = bs_ - sgnf(llr_s[s]) * Pst[s][kis];
            dval = phi_f(bX1 + (phi_f(bis) - cbA[s]));
        } else {
            dval = phi_f(bX1);
        }

        // ---- step A (Ts) ----
        const unsigned long long lanelt = (1ull << ln) - 1ull;
        const int  kjA  = (int)rowpre[s][wv] + __popcll(rmA & lanelt);
        const bool hitA = (rmA >> ln) & 1ull;
        float sumA = 0.0f;
        sumA += gA0; sumA += gA1; sumA += gA2; sumA += gA3; sumA += gA4; sumA += gA5;
        for (int k = CLU; k < cd; ++k) sumA += cbA[clistT[k][j]];
        const float baseA = sumA - sgj * Pst[s][kjA];
        const bool hvA = hitA && (j > s);
        float biA = 0.f, cbsA = 0.f;
        if (hvA) {
            float bsum = 0.0f;
            const int cds = cdeg_s[s];
            for (int k = 0; k < cds; ++k) bsum += cbA[clistT[k][s]];
            const int kis2 = (int)rowpre[s][s >> 6]
                           + __popcll(rowmask[s][s >> 6] & ((1ull << (s & 63)) - 1ull));
            biA  = bsum - sgnf(llr_s[s]) * Pst[s][kis2];
            cbsA = cbA[s];
        }

        // ---- step B (Ts+1): substitute cell s -> dval everywhere ----
        const int  kjB  = (int)rowpre[X1v][wv] + __popcll(rmB & lanelt);
        const bool hitB = (rmB >> ln) & 1ull;
        const float tB0 = (cl0 == s) ? dval : gB0;
        const float tB1 = (cl1 == s) ? dval : gB1;
        const float tB2 = (cl2 == s) ? dval : gB2;
        const float tB3 = (cl3 == s) ? dval : gB3;
        const float tB4 = (cl4 == s) ? dval : gB4;
        const float tB5 = (cl5 == s) ? dval : gB5;
        float sumB = 0.0f;
        sumB += tB0; sumB += tB1; sumB += tB2; sumB += tB3; sumB += tB4; sumB += tB5;
        for (int k = CLU; k < cd; ++k) {
            const int ci = clistT[k][j];
            sumB += (ci == s) ? dval : cbB[ci];
        }
        const float baseB = sumB - sgj * Pst[X1v][kjB];
        const bool hvB = hitB && (j > X1v);
        float biB = 0.f, cbsB = 0.f;
        if (hvB) {
            float bsum = 0.0f;
            const int cdsB = cdeg_s[X1v];
            for (int k = 0; k < cdsB; ++k) {
                const int ci = clistT[k][X1v];
                bsum += (ci == s) ? dval : cbB[ci];
            }
            const int kiB = (int)rowpre[X1v][X1v >> 6]
                          + __popcll(rowmask[X1v][X1v >> 6] & ((1ull << (X1v & 63)) - 1ull));
            biB  = bsum - sgnf(llr_s[X1v]) * Pst[X1v][kiB];
            cbsB = cbB[X1v];                                 // X1v != s: no substitution
        }

        // ---- owners: patch 4 fresh cells of next-section columns (own registers only) ----
        if (j == X2v || j == X3v) {
            float voT, voT1;
            if (hvA) voT  = phi_f(baseA + (phi_f(biA) - cbsA)); else voT  = phi_f(baseA);
            if (hvB) voT1 = phi_f(baseB + (phi_f(biB) - cbsB)); else voT1 = phi_f(baseB);
            float* nx = (j == X2v) ? nxA : nxB;
            nx[s]   = voT;                                   // producer Ts
            nx[X1v] = voT1;                                  // producer Ts+1
            if (Ts >= 2) {
                nx[(Ts - 1) & 255] = vnpB;                   // producer Ts-1 (own deferred)
                nx[(Ts - 2) & 255] = vnpA;                   // producer Ts-2 (own deferred)
            }
        }

        // ---- generic staging: producers <= Ts-3 (ring rows barrier-separated) ----
        if (p <= Ts - 3) {
            float vA, vB;
            if (p < 0)           { vA = 0.0f;   vB = 0.0f;   }
            else if (p >= Ts - 8){ vA = ringvA; vB = ringvB; }
            else                 { vA = pfu0;   vB = pfu1;   }
            nxA[j] = vA;
            nxB[j] = vB;
        }

        svA_base = baseA; svA_bi = biA; svA_cbs = cbsA; svA_hv = hvA ? 1 : 0;
        svB_base = baseB; svB_bi = biB; svB_cbs = cbsB; svB_hv = hvB ? 1 : 0;
        pfu0 = pfi0; pfu1 = pfi1;

        lds_barrier();                                       // one barrier per 2 steps
    }

    // ---- epilogue: rows total-2, total-1, then output (threads 0..3) ----
    {
        float vnpA, vnpB;
        if (svA_hv) { float vn = phi_f(svA_bi); vnpA = phi_f(svA_base + (vn - svA_cbs)); }
        else        vnpA = phi_f(svA_base);
        if (svB_hv) { float vn = phi_f(svB_bi); vnpB = phi_f(svB_base + (vn - svB_cbs)); }
        else        vnpB = phi_f(svB_base);
        if (j < 4) {
            fprod *= tanhf(0.5f * vnpA);                     // row total-2
            fprod *= tanhf(0.5f * vnpB);                     // row total-1
            const float soft = sgj * fprod;
            out_g[j] = (soft > 0.0f) ? 1 : 0;
        }
    }
}

extern "C" void kernel_launch(void* const* d_in, const int* in_sizes, int n_in,
                              void* d_out, int out_size, void* d_ws, size_t ws_size,
                              hipStream_t stream) {
    const float* llr = (const float*)d_in[0];
    const int*   H   = (const int*)d_in[1];
    const int*   mi  = (const int*)d_in[2];
    int*         out = (int*)d_out;
    float*       ws  = (float*)d_ws;
    hipLaunchKernelGGL(ldpc_bp9, dim3(1), dim3(256), 0, stream,
                       llr, H, mi, out, ws);
}